// Round 2
// baseline (349.250 us; speedup 1.0000x reference)
//
#include <hip/hip_runtime.h>

namespace {
constexpr int Bn = 16, Cn = 8, Hn = 512, Wn = 512;
constexpr int HW  = Hn * Wn;        // 262144
constexpr int CHW = Cn * HW;        // 2097152
constexpr int NCOL = Bn * Wn;       // 8192 dice columns
constexpr int ROWS = 8;             // rows per block
constexpr int GY   = Hn / ROWS;     // 64
constexpr int NBLK = GY * Bn;       // 1024 blocks
constexpr int FBLK = 32;            // finisher blocks (32*256 == NCOL)

__device__ __forceinline__ float frcp(float x) { return __builtin_amdgcn_rcpf(x); }
} // namespace

// n[c](h,w) = sigmoid(c_map[c][h+DY[c]][w+DX[c]]), zero outside image.
// vote[i] = p[i] * n[7-i].  DX = {1,0,-1,1,-1,1,0,-1}, DY = {1,1,1,0,0,-1,-1,-1}.
// Wave covers the full 512-wide row (8 px/lane) so dx shifts are in-register.

__global__ __launch_bounds__(256) void bicon_main(
    const float* __restrict__ c_map,
    const int*   __restrict__ target,
    const int*   __restrict__ con_target,
    float* __restrict__ col_i, float* __restrict__ col_j, float* __restrict__ col_x,
    double* __restrict__ bscal)
{
    const int tx = threadIdx.x;          // lane 0..63
    const int ty = threadIdx.y;          // wave 0..3 (row phase)
    const int b  = blockIdx.y;
    const int h0 = blockIdx.x * ROWS;
    const int wq = tx << 3;              // 8 pixels per lane -> full row

    const float* cm = c_map      + (size_t)b * CHW;
    const int*   ct = con_target + (size_t)b * CHW;
    const int*   tg = target     + (size_t)b * HW;

    float s_con = 0.f, s_bi = 0.f, s_bce = 0.f, s_dec = 0.f;
    float ci[8], cj[8], cx[8];
#pragma unroll
    for (int k = 0; k < 8; ++k) { ci[k] = cj[k] = cx[k] = 0.f; }

#pragma unroll
    for (int it = 0; it < ROWS / 4; ++it) {
        const int h    = h0 + ty + it * 4;
        const int base = h * Wn + wq;

        // ---- con_target: pack 8 channel bits per pixel ----
        int tp[8] = {0, 0, 0, 0, 0, 0, 0, 0};
#pragma unroll
        for (int c = 0; c < 8; ++c) {
            const int4 u0 = *(const int4*)(ct + c * HW + base);
            const int4 u1 = *(const int4*)(ct + c * HW + base + 4);
            tp[0] |= u0.x << c; tp[1] |= u0.y << c; tp[2] |= u0.z << c; tp[3] |= u0.w << c;
            tp[4] |= u1.x << c; tp[5] |= u1.y << c; tp[6] |= u1.z << c; tp[7] |= u1.w << c;
        }

        float vmax[8], vmin[8];
#pragma unroll
        for (int k = 0; k < 8; ++k) { vmax[k] = 0.f; vmin[k] = 2.f; }

        // center sigmoid of channel c + fused conmap BCE term
        // log(s) = -log d, log(1-s) = -x - log d  with d = 1 + e^-x
        auto center = [&](int c, float s[8]) {
            const float* p = cm + c * HW + base;
            const float4 v0 = *(const float4*)p;
            const float4 v1 = *(const float4*)(p + 4);
            const float xs[8] = {v0.x, v0.y, v0.z, v0.w, v1.x, v1.y, v1.z, v1.w};
#pragma unroll
            for (int k = 0; k < 8; ++k) {
                const float e = __expf(-xs[k]);
                const float d = 1.f + e;
                s[k] = frcp(d);
                const float logd = __logf(d);
                const float term = ((tp[k] >> c) & 1) ? -logd : (-xs[k] - logd);
                s_con += fmaxf(term, -100.f);
            }
        };

        // neighbor row (h+dy) sigmoids of channel c; zero row outside image
        auto nbrrow = [&](int c, int dy, float sp[8]) {
            const int hn = h + dy;
            if ((unsigned)hn < (unsigned)Hn) {     // wave-uniform branch
                const float* p = cm + c * HW + hn * Wn + wq;
                const float4 v0 = *(const float4*)p;
                const float4 v1 = *(const float4*)(p + 4);
                const float xs[8] = {v0.x, v0.y, v0.z, v0.w, v1.x, v1.y, v1.z, v1.w};
#pragma unroll
                for (int k = 0; k < 8; ++k) sp[k] = frcp(1.f + __expf(-xs[k]));
            } else {
#pragma unroll
                for (int k = 0; k < 8; ++k) sp[k] = 0.f;
            }
        };

        auto shplus = [&](const float sp[8], float n[8]) {   // value at w+1
#pragma unroll
            for (int k = 0; k < 7; ++k) n[k] = sp[k + 1];
            const float t = __shfl_down(sp[0], 1);
            n[7] = (tx == 63) ? 0.f : t;
        };
        auto shminus = [&](const float sp[8], float n[8]) {  // value at w-1
#pragma unroll
            for (int k = 7; k > 0; --k) n[k] = sp[k - 1];
            const float t = __shfl_up(sp[7], 1);
            n[0] = (tx == 0) ? 0.f : t;
        };

        auto vote = [&](int i, const float si[8], const float nn[8]) {
#pragma unroll
            for (int k = 0; k < 8; ++k) {
                const float v = si[k] * nn[k];
                vmax[k] = fmaxf(vmax[k], v);
                vmin[k] = fminf(vmin[k], v);
                const float arg = ((tp[k] >> i) & 1) ? v : (1.f - v);
                s_bi += fmaxf(__logf(arg), -100.f);
            }
        };

        { // pair (0,7)
            float sa[8], sb[8], sp[8], n[8];
            center(0, sa); center(7, sb);
            nbrrow(0, +1, sp); shplus(sp, n);  vote(7, sb, n);
            nbrrow(7, -1, sp); shminus(sp, n); vote(0, sa, n);
        }
        { // pair (1,6) — dx = 0, no shift
            float sa[8], sb[8], sp[8];
            center(1, sa); center(6, sb);
            nbrrow(1, +1, sp); vote(6, sb, sp);
            nbrrow(6, -1, sp); vote(1, sa, sp);
        }
        { // pair (2,5)
            float sa[8], sb[8], sp[8], n[8];
            center(2, sa); center(5, sb);
            nbrrow(2, +1, sp); shminus(sp, n); vote(5, sb, n);
            nbrrow(5, -1, sp); shplus(sp, n);  vote(2, sa, n);
        }
        { // pair (3,4) — dy = 0, reuse center sigmoids
            float sa[8], sb[8], n[8];
            center(3, sa); center(4, sb);
            shplus(sa, n);  vote(4, sb, n);
            shminus(sb, n); vote(3, sa, n);
        }

        // ---- per-pixel tail: bce, decouple, dice partials ----
        const int4 t0 = *(const int4*)(tg + base);
        const int4 t1 = *(const int4*)(tg + base + 4);
        const int tk[8] = {t0.x, t0.y, t0.z, t0.w, t1.x, t1.y, t1.z, t1.w};
#pragma unroll
        for (int k = 0; k < 8; ++k) {
            const float fm = vmax[k];
            s_bce += fmaxf(__logf(tk[k] ? fm : 1.f - fm), -100.f);
            const int sc = __popc(tp[k]);
            const float le = fmaxf(__logf(1.f - vmin[k]), -100.f);
            s_dec += (sc > 0 && sc < 8) ? le : 0.f;  // edge mask
            ci[k] += (float)tk[k];
            cj[k] += fm;
            cx[k] += tk[k] ? fm : 0.f;
        }
    }

    // ---- dice partials: reduce over the 4 row-phase waves via LDS ----
    __shared__ float cred[3][4][512];   // 24 KB
#pragma unroll
    for (int k = 0; k < 8; ++k) {
        cred[0][ty][wq + k] = ci[k];
        cred[1][ty][wq + k] = cj[k];
        cred[2][ty][wq + k] = cx[k];
    }

    // ---- scalar sums: wave shuffle reduction ----
#pragma unroll
    for (int off = 32; off > 0; off >>= 1) {
        s_con += __shfl_down(s_con, off);
        s_bi  += __shfl_down(s_bi,  off);
        s_bce += __shfl_down(s_bce, off);
        s_dec += __shfl_down(s_dec, off);
    }
    __shared__ float wred[4][4];
    if (tx == 0) {
        wred[ty][0] = s_con; wred[ty][1] = s_bi;
        wred[ty][2] = s_bce; wred[ty][3] = s_dec;
    }
    __syncthreads();

    const int tid = ty * 64 + tx;
#pragma unroll
    for (int j = tid; j < 512; j += 256) {
        const float a0 = cred[0][0][j] + cred[0][1][j] + cred[0][2][j] + cred[0][3][j];
        const float a1 = cred[1][0][j] + cred[1][1][j] + cred[1][2][j] + cred[1][3][j];
        const float a2 = cred[2][0][j] + cred[2][1][j] + cred[2][2][j] + cred[2][3][j];
        atomicAdd(&col_i[b * Wn + j], a0);
        atomicAdd(&col_j[b * Wn + j], a1);
        atomicAdd(&col_x[b * Wn + j], a2);
    }
    if (tid < 4) {
        bscal[((size_t)blockIdx.y * GY + blockIdx.x) * 4 + tid] =
            (double)(wred[0][tid] + wred[1][tid] + wred[2][tid] + wred[3][tid]);
    }
}

__global__ __launch_bounds__(256) void bicon_finish(
    const float* __restrict__ col_i,
    const float* __restrict__ col_j,
    const float* __restrict__ col_x,
    const double* __restrict__ bscal,
    float* __restrict__ out)
{
    const int tid = threadIdx.x;
    const int col = blockIdx.x * 256 + tid;      // exactly NCOL threads total

    double part;
    {
        const float fi = col_i[col], fj = col_j[col], fx = col_x[col];
        part = (1.0 - (2.0 * (double)fx + 0.001) /
                      ((double)fi + (double)fj + 0.001)) / 8192.0;
    }
    if (tid < 32) {   // 32 bscal slots per block: 32 blocks * 32 = 1024
        const int s = blockIdx.x * 32 + tid;
        const double c0 = bscal[s * 4 + 0], c1 = bscal[s * 4 + 1];
        const double c2 = bscal[s * 4 + 2], c3 = bscal[s * 4 + 3];
        part += -0.8 * c0 / 33554432.0 - 0.2 * c1 / 33554432.0
                - c2 / 4194304.0 - c3 / 4194304.0;
    }
#pragma unroll
    for (int off = 32; off > 0; off >>= 1) part += __shfl_down(part, off);
    __shared__ double red[4];
    if ((tid & 63) == 0) red[tid >> 6] = part;
    __syncthreads();
    if (tid == 0) atomicAdd(out, (float)(red[0] + red[1] + red[2] + red[3]));
}

extern "C" void kernel_launch(void* const* d_in, const int* in_sizes, int n_in,
                              void* d_out, int out_size, void* d_ws, size_t ws_size,
                              hipStream_t stream) {
    const float* c_map      = (const float*)d_in[0];
    const int*   target     = (const int*)d_in[1];
    const int*   con_target = (const int*)d_in[2];
    float* out = (float*)d_out;

    char* ws = (char*)d_ws;
    float*  col_i = (float*)ws;                               // 8192 floats
    float*  col_j = col_i + NCOL;
    float*  col_x = col_j + NCOL;
    double* bscal = (double*)(ws + 3 * NCOL * sizeof(float)); // 1024*4 doubles

    hipMemsetAsync(d_ws, 0, 3 * NCOL * sizeof(float), stream); // zero col tables
    hipMemsetAsync(d_out, 0, sizeof(float), stream);           // finisher atomics into this

    dim3 grid(GY, Bn);       // 64 x 16 = 1024 blocks
    dim3 block(64, 4);
    bicon_main<<<grid, block, 0, stream>>>(c_map, target, con_target,
                                           col_i, col_j, col_x, bscal);
    bicon_finish<<<FBLK, 256, 0, stream>>>(col_i, col_j, col_x, bscal, out);
}

// Round 3
// 348.306 us; speedup vs baseline: 1.0027x; 1.0027x over previous
//
#include <hip/hip_runtime.h>

namespace {
constexpr int Bn = 16, Cn = 8, Hn = 512, Wn = 512;
constexpr int HW  = Hn * Wn;        // 262144
constexpr int CHW = Cn * HW;        // 2097152
constexpr int NCOL = Bn * Wn;       // 8192 dice columns
constexpr int GX   = Hn / 4;        // 128 row-groups (4 rows per block, 1 per wave)
constexpr int NBLK = GX * Bn;       // 2048 blocks
constexpr int FBLK = 32;            // finisher blocks (32*256 == NCOL)

__device__ __forceinline__ float frcp(float x) { return __builtin_amdgcn_rcpf(x); }
} // namespace

// n[c](h,w) = sigmoid(c_map[c][h+DY[c]][w+DX[c]]), zero outside image.
// vote[i] = p[i] * n[7-i].  DX = {1,0,-1,1,-1,1,0,-1}, DY = {1,1,1,0,0,-1,-1,-1}.
// One wave == one full 512-px row (8 px/lane): dx shifts are in-register + 1 shuffle.

__global__ __launch_bounds__(256, 4) void bicon_main(
    const float* __restrict__ c_map,
    const int*   __restrict__ target,
    const int*   __restrict__ con_target,
    float* __restrict__ col_i, float* __restrict__ col_j, float* __restrict__ col_x,
    double* __restrict__ bscal)
{
    const int tx = threadIdx.x;          // lane 0..63
    const int ty = threadIdx.y;          // wave 0..3 -> row within group
    const int b  = blockIdx.y;
    const int h  = blockIdx.x * 4 + ty;  // this wave's row
    const int wq = tx << 3;              // 8 px per lane -> full row per wave
    const int base = h * Wn + wq;

    const float* cm = c_map      + (size_t)b * CHW;
    const int*   ct = con_target + (size_t)b * CHW;
    const int*   tg = target     + (size_t)b * HW;

    // ---- con_target: pack 8 channel bits x 8 px into 2 uints (byte per px) ----
    unsigned lo = 0u, hi = 0u;
#pragma unroll
    for (int c = 0; c < 8; ++c) {
        const int4 u0 = *(const int4*)(ct + c * HW + base);
        const int4 u1 = *(const int4*)(ct + c * HW + base + 4);
        lo |= ((unsigned)u0.x << c) | ((unsigned)u0.y << (8 + c)) |
              ((unsigned)u0.z << (16 + c)) | ((unsigned)u0.w << (24 + c));
        hi |= ((unsigned)u1.x << c) | ((unsigned)u1.y << (8 + c)) |
              ((unsigned)u1.z << (16 + c)) | ((unsigned)u1.w << (24 + c));
    }
    auto bit = [&](int k, int c) -> int {
        return (int)(((k < 4 ? lo >> (8 * k + c) : hi >> (8 * (k - 4) + c))) & 1u);
    };

    float s_con = 0.f, s_bi = 0.f, s_bce = 0.f, s_dec = 0.f;
    float vmax[8], vmin[8];
#pragma unroll
    for (int k = 0; k < 8; ++k) { vmax[k] = 0.f; vmin[k] = 2.f; }

    // center sigmoid of channel c + fused conmap BCE term:
    // log(s) = -log d, log(1-s) = -x - log d, d = 1 + e^-x
    auto center = [&](int c, float s[8]) {
        const float* p = cm + c * HW + base;
        const float4 v0 = *(const float4*)p;
        const float4 v1 = *(const float4*)(p + 4);
        const float xs[8] = {v0.x, v0.y, v0.z, v0.w, v1.x, v1.y, v1.z, v1.w};
#pragma unroll
        for (int k = 0; k < 8; ++k) {
            const float e = __expf(-xs[k]);
            const float d = 1.f + e;
            s[k] = frcp(d);
            const float logd = __logf(d);
            s_con += fmaxf(bit(k, c) ? -logd : (-xs[k] - logd), -100.f);
        }
    };
    // neighbor row (h+dy) sigmoids of channel c; zero row outside image
    auto nbrrow = [&](int c, int dy, float sp[8]) {
        const int hn = h + dy;
        if ((unsigned)hn < (unsigned)Hn) {   // wave-uniform branch
            const float* p = cm + c * HW + hn * Wn + wq;
            const float4 v0 = *(const float4*)p;
            const float4 v1 = *(const float4*)(p + 4);
            const float xs[8] = {v0.x, v0.y, v0.z, v0.w, v1.x, v1.y, v1.z, v1.w};
#pragma unroll
            for (int k = 0; k < 8; ++k) sp[k] = frcp(1.f + __expf(-xs[k]));
        } else {
#pragma unroll
            for (int k = 0; k < 8; ++k) sp[k] = 0.f;
        }
    };
    auto shplus = [&](const float sp[8], float n[8]) {   // value at w+1
#pragma unroll
        for (int k = 0; k < 7; ++k) n[k] = sp[k + 1];
        const float t = __shfl_down(sp[0], 1);
        n[7] = (tx == 63) ? 0.f : t;
    };
    auto shminus = [&](const float sp[8], float n[8]) {  // value at w-1
#pragma unroll
        for (int k = 7; k > 0; --k) n[k] = sp[k - 1];
        const float t = __shfl_up(sp[7], 1);
        n[0] = (tx == 0) ? 0.f : t;
    };
    auto vote = [&](int i, const float si[8], const float nn[8]) {
#pragma unroll
        for (int k = 0; k < 8; ++k) {
            const float v = si[k] * nn[k];
            vmax[k] = fmaxf(vmax[k], v);
            vmin[k] = fminf(vmin[k], v);
            s_bi += fmaxf(__logf(bit(k, i) ? v : 1.f - v), -100.f);
        }
    };

    { // pair (0,7)
        float sa[8], sb[8], sp[8], n[8];
        center(0, sa); center(7, sb);
        nbrrow(0, +1, sp); shplus(sp, n);  vote(7, sb, n);
        nbrrow(7, -1, sp); shminus(sp, n); vote(0, sa, n);
    }
    { // pair (1,6) — dx = 0, no shift
        float sa[8], sb[8], sp[8];
        center(1, sa); center(6, sb);
        nbrrow(1, +1, sp); vote(6, sb, sp);
        nbrrow(6, -1, sp); vote(1, sa, sp);
    }
    { // pair (2,5)
        float sa[8], sb[8], sp[8], n[8];
        center(2, sa); center(5, sb);
        nbrrow(2, +1, sp); shminus(sp, n); vote(5, sb, n);
        nbrrow(5, -1, sp); shplus(sp, n);  vote(2, sa, n);
    }
    { // pair (3,4) — dy = 0, reuse center sigmoids
        float sa[8], sb[8], n[8];
        center(3, sa); center(4, sb);
        shplus(sa, n);  vote(4, sb, n);
        shminus(sb, n); vote(3, sa, n);
    }

    // ---- per-pixel tail: bce, decouple, dice contributions ----
    const int4 t0 = *(const int4*)(tg + base);
    const int4 t1 = *(const int4*)(tg + base + 4);
    const int tk[8] = {t0.x, t0.y, t0.z, t0.w, t1.x, t1.y, t1.z, t1.w};

    __shared__ float cred[3][4][512];   // 24 KB
#pragma unroll
    for (int k = 0; k < 8; ++k) {
        const float fm = vmax[k];
        s_bce += fmaxf(__logf(tk[k] ? fm : 1.f - fm), -100.f);
        const int sc = __popc((int)((k < 4 ? lo >> (8 * k) : hi >> (8 * (k - 4))) & 0xffu));
        const float le = fmaxf(__logf(1.f - vmin[k]), -100.f);
        s_dec += (sc > 0 && sc < 8) ? le : 0.f;    // edge mask
        cred[0][ty][wq + k] = (float)tk[k];
        cred[1][ty][wq + k] = fm;
        cred[2][ty][wq + k] = tk[k] ? fm : 0.f;
    }

    // ---- scalar sums: wave shuffle reduction ----
#pragma unroll
    for (int off = 32; off > 0; off >>= 1) {
        s_con += __shfl_down(s_con, off);
        s_bi  += __shfl_down(s_bi,  off);
        s_bce += __shfl_down(s_bce, off);
        s_dec += __shfl_down(s_dec, off);
    }
    __shared__ float wred[4][4];
    if (tx == 0) {
        wred[ty][0] = s_con; wred[ty][1] = s_bi;
        wred[ty][2] = s_bce; wred[ty][3] = s_dec;
    }
    __syncthreads();

    const int tid = ty * 64 + tx;
#pragma unroll
    for (int j = tid; j < 512; j += 256) {
        const float a0 = cred[0][0][j] + cred[0][1][j] + cred[0][2][j] + cred[0][3][j];
        const float a1 = cred[1][0][j] + cred[1][1][j] + cred[1][2][j] + cred[1][3][j];
        const float a2 = cred[2][0][j] + cred[2][1][j] + cred[2][2][j] + cred[2][3][j];
        atomicAdd(&col_i[b * Wn + j], a0);
        atomicAdd(&col_j[b * Wn + j], a1);
        atomicAdd(&col_x[b * Wn + j], a2);
    }
    if (tid < 4) {
        bscal[((size_t)blockIdx.y * GX + blockIdx.x) * 4 + tid] =
            (double)(wred[0][tid] + wred[1][tid] + wred[2][tid] + wred[3][tid]);
    }
}

__global__ __launch_bounds__(256) void bicon_finish(
    const float* __restrict__ col_i,
    const float* __restrict__ col_j,
    const float* __restrict__ col_x,
    const double* __restrict__ bscal,
    float* __restrict__ out)
{
    const int tid = threadIdx.x;
    const int col = blockIdx.x * 256 + tid;      // exactly NCOL threads total

    double part;
    {
        const float fi = col_i[col], fj = col_j[col], fx = col_x[col];
        part = (1.0 - (2.0 * (double)fx + 0.001) /
                      ((double)fi + (double)fj + 0.001)) / 8192.0;
    }
    if (tid < 64) {   // 64 bscal slots per block: 32 blocks * 64 = 2048
        const int s = blockIdx.x * 64 + tid;
        const double c0 = bscal[s * 4 + 0], c1 = bscal[s * 4 + 1];
        const double c2 = bscal[s * 4 + 2], c3 = bscal[s * 4 + 3];
        part += -0.8 * c0 / 33554432.0 - 0.2 * c1 / 33554432.0
                - c2 / 4194304.0 - c3 / 4194304.0;
    }
#pragma unroll
    for (int off = 32; off > 0; off >>= 1) part += __shfl_down(part, off);
    __shared__ double red[4];
    if ((tid & 63) == 0) red[tid >> 6] = part;
    __syncthreads();
    if (tid == 0) atomicAdd(out, (float)(red[0] + red[1] + red[2] + red[3]));
}

extern "C" void kernel_launch(void* const* d_in, const int* in_sizes, int n_in,
                              void* d_out, int out_size, void* d_ws, size_t ws_size,
                              hipStream_t stream) {
    const float* c_map      = (const float*)d_in[0];
    const int*   target     = (const int*)d_in[1];
    const int*   con_target = (const int*)d_in[2];
    float* out = (float*)d_out;

    char* ws = (char*)d_ws;
    float*  col_i = (float*)ws;                               // 8192 floats
    float*  col_j = col_i + NCOL;
    float*  col_x = col_j + NCOL;
    double* bscal = (double*)(ws + 3 * NCOL * sizeof(float)); // 2048*4 doubles

    hipMemsetAsync(d_ws, 0, 3 * NCOL * sizeof(float), stream); // zero col tables
    hipMemsetAsync(d_out, 0, sizeof(float), stream);           // finisher atomics here

    dim3 grid(GX, Bn);       // 128 x 16 = 2048 blocks
    dim3 block(64, 4);
    bicon_main<<<grid, block, 0, stream>>>(c_map, target, con_target,
                                           col_i, col_j, col_x, bscal);
    bicon_finish<<<FBLK, 256, 0, stream>>>(col_i, col_j, col_x, bscal, out);
}